// Round 8
// baseline (119.923 us; speedup 1.0000x reference)
//
#include <hip/hip_runtime.h>

// CLUB loss, algebraically collapsed (O(N*d), x read once):
//   out = -0.5/N * P + 0.5/N^2 * ( <Sx2,Sinv> - 2<Sx,Smuinv> + N*Smu2inv )
// Sinv[d]=sum_i e^{-lv}, Smuinv[d]=sum_i mu e^{-lv}, Sx[d]=sum_j x, Sx2[d]=sum_j x^2
// P = sum (x-mu)^2 e^{-lv},  Smu2inv = sum mu^2 e^{-lv}
//
// R8: max-MLP column-private. Thread owns ONE column d for a 16-row chunk:
//  - x slice = exactly one 64B line per thread (hw0 = 16*chunk -> 64B aligned).
//  - mu/lv: 32 coalesced scalar loads (256B/wave-instr).
//  - ALL 36 loads issued before any compute -> deep MLP, zero barriers.
//  - 784 blocks (~12 waves/CU), 64-rep atomic fanout, last-block finalize.

#define Dd   512
#define HWs  784
#define Nn   6272
#define NBLK 784      // 8 b * 2 col-halves * 49 row-chunks (16 rows each)
#define REP  64

// ws floats: Inv rep*512+c | Mu 32768+ | Sx 65536+ | Sx2 98304+  (rep<64)
// doubles @byte 524288: P[64], M2[64].  uint counter @byte 525312.

__global__ __launch_bounds__(256) void club_all(
    const float* __restrict__ x, const float* __restrict__ p_mu,
    const float* __restrict__ p_lv, float* __restrict__ ws,
    float* __restrict__ out)
{
    __shared__ float sbuf[16];
    __shared__ int lastFlag;
    __shared__ double redd[256];

    const int t     = threadIdx.x;
    const int blk   = blockIdx.x;
    const int b     = blk / 98;
    const int rem   = blk % 98;
    const int half  = rem & 1;
    const int chunk = rem >> 1;          // 0..48
    const int hw0   = chunk * 16;
    const int c     = 256 * half + t;    // this thread's column
    const int r0    = b * HWs + hw0;
    const int rep   = blk & (REP - 1);

    // ---- issue ALL loads up front (4 dwordx4 + 32 dword, independent) ----
    const float* xr = x + ((size_t)(b * Dd + c) * HWs + hw0);  // 64B-aligned line
    const float4 xq0 = *(const float4*)(xr + 0);
    const float4 xq1 = *(const float4*)(xr + 4);
    const float4 xq2 = *(const float4*)(xr + 8);
    const float4 xq3 = *(const float4*)(xr + 12);

    const float* mp = p_mu + (size_t)r0 * Dd + c;
    const float* lp = p_lv + (size_t)r0 * Dd + c;
    float mu[16], lv[16];
#pragma unroll
    for (int j = 0; j < 16; ++j) mu[j] = mp[(size_t)j * Dd];
#pragma unroll
    for (int j = 0; j < 16; ++j) lv[j] = lp[(size_t)j * Dd];

    float sI = 0.f, sM = 0.f, sX = 0.f, sX2 = 0.f, aP = 0.f, aM2 = 0.f;
    float xv[16] = {xq0.x, xq0.y, xq0.z, xq0.w, xq1.x, xq1.y, xq1.z, xq1.w,
                    xq2.x, xq2.y, xq2.z, xq2.w, xq3.x, xq3.y, xq3.z, xq3.w};
#pragma unroll
    for (int j = 0; j < 16; ++j) {
        const float iev = __expf(-lv[j]);
        const float dd  = xv[j] - mu[j];
        aP += dd * dd * iev;
        sI += iev;
        const float mi = mu[j] * iev;
        sM += mi; aM2 += mu[j] * mi;
        sX += xv[j]; sX2 += xv[j] * xv[j];
    }

    // ---- scalar P/M2: wave shuffle -> LDS -> one double atomic each ----
#pragma unroll
    for (int off = 32; off > 0; off >>= 1) {
        aP  += __shfl_down(aP,  off);
        aM2 += __shfl_down(aM2, off);
    }
    if ((t & 63) == 0) { sbuf[t >> 6] = aP; sbuf[8 + (t >> 6)] = aM2; }
    __syncthreads();     // only barrier before finalize

    // ---- fire-and-forget atomics: own column, 64-way replicas ----
    atomicAdd(&ws[(0 * REP + rep) * Dd + c], sI);
    atomicAdd(&ws[(1 * REP + rep) * Dd + c], sM);
    atomicAdd(&ws[(2 * REP + rep) * Dd + c], sX);
    atomicAdd(&ws[(3 * REP + rep) * Dd + c], sX2);
    if (t == 0) {
        double* wd = (double*)((char*)ws + 524288);
        atomicAdd(wd + rep,       (double)(sbuf[0] + sbuf[1] + sbuf[2] + sbuf[3]));
        atomicAdd(wd + REP + rep, (double)(sbuf[8] + sbuf[9] + sbuf[10] + sbuf[11]));
    }

    // ---- last-block-done finalize ----
    if (t == 0) {
        __threadfence();
        unsigned* ctr = (unsigned*)((char*)ws + 525312);
        lastFlag = (atomicAdd(ctr, 1u) == NBLK - 1);
    }
    __syncthreads();
    if (!lastFlag) return;

    __threadfence();
    double dc = 0.0;
#pragma unroll
    for (int hh = 0; hh < 2; ++hh) {
        const int cc = t + 256 * hh;
        double vI = 0.0, vM = 0.0, vX = 0.0, v2 = 0.0;
        for (int r = 0; r < REP; ++r) {
            vI += (double)__hip_atomic_load(ws + (0 * REP + r) * Dd + cc, __ATOMIC_RELAXED, __HIP_MEMORY_SCOPE_AGENT);
            vM += (double)__hip_atomic_load(ws + (1 * REP + r) * Dd + cc, __ATOMIC_RELAXED, __HIP_MEMORY_SCOPE_AGENT);
            vX += (double)__hip_atomic_load(ws + (2 * REP + r) * Dd + cc, __ATOMIC_RELAXED, __HIP_MEMORY_SCOPE_AGENT);
            v2 += (double)__hip_atomic_load(ws + (3 * REP + r) * Dd + cc, __ATOMIC_RELAXED, __HIP_MEMORY_SCOPE_AGENT);
        }
        dc += v2 * vI - 2.0 * vX * vM;
    }
    redd[t] = dc; __syncthreads();
    for (int s = 128; s > 0; s >>= 1) {
        if (t < s) redd[t] += redd[t + s];
        __syncthreads();
    }
    if (t == 0) {
        double* wd = (double*)((char*)ws + 524288);
        double P = 0.0, M2 = 0.0;
#pragma unroll
        for (int r = 0; r < REP; ++r) {
            P  += __hip_atomic_load(wd + r,       __ATOMIC_RELAXED, __HIP_MEMORY_SCOPE_AGENT);
            M2 += __hip_atomic_load(wd + REP + r, __ATOMIC_RELAXED, __HIP_MEMORY_SCOPE_AGENT);
        }
        const double sumD = redd[0] + (double)Nn * M2;
        out[0] = (float)((-0.5 / (double)Nn) * P
                       + (0.5 / ((double)Nn * (double)Nn)) * sumD);
    }
}

extern "C" void kernel_launch(void* const* d_in, const int* in_sizes, int n_in,
                              void* d_out, int out_size, void* d_ws, size_t ws_size,
                              hipStream_t stream) {
    const float* x    = (const float*)d_in[0];
    const float* p_mu = (const float*)d_in[1];
    const float* p_lv = (const float*)d_in[2];
    float* ws = (float*)d_ws;

    // zero: 512KB float accumulators + 128 doubles + counter
    hipMemsetAsync(d_ws, 0, 525316, stream);
    club_all<<<NBLK, 256, 0, stream>>>(x, p_mu, p_lv, ws, (float*)d_out);
}